// Round 8
// baseline (558.583 us; speedup 1.0000x reference)
//
#include <hip/hip_runtime.h>
#include <math.h>

// ---------------------------------------------------------------------------
// 3-layer GCN, CSR-gather formulation.
// Round 8: GEMMs rebuilt in the k_w3lsm pattern (W column pinned in VGPRs,
// X row read via wave-uniform address). The 4x4-tile GEMM was L1-pipe bound:
// W loads 4x-replicated and X loads 16x-replicated per wave (8KB requested
// per 1.25KB unique) -> 68us vs ~10us floor.
// N=100000, E=1200000, F: 128 -> 64 -> 64 -> 40
// ---------------------------------------------------------------------------

static inline int cdiv(long a, int b) { return (int)((a + b - 1) / b); }

__global__ void k_zero_i32(int* __restrict__ p, int n) {
    int i = blockIdx.x * blockDim.x + threadIdx.x;
    if (i < n) p[i] = 0;
}

__global__ void k_hist(const int* __restrict__ dst, int* __restrict__ cnt, int E) {
    int i = blockIdx.x * blockDim.x + threadIdx.x;
    if (i < E) atomicAdd(&cnt[dst[i]], 1);
}

__global__ void k_dis(const int* __restrict__ cnt, float* __restrict__ dis, int n) {
    int i = blockIdx.x * blockDim.x + threadIdx.x;
    if (i < n) dis[i] = rsqrtf(1.0f + (float)cnt[i]);  // +1 self-loop
}

// ---- 3-step exclusive scan of cnt[0..n) into rp[0..n], rp[n]=E ----
#define SCAN_B 1024
__global__ void k_scan1(const int* __restrict__ cnt, int* __restrict__ rp,
                        int* __restrict__ bsum, int n) {
    __shared__ int sm[SCAN_B];
    const int tid = threadIdx.x;
    const int gid = blockIdx.x * SCAN_B + tid;
    int v = (gid < n) ? cnt[gid] : 0;
    sm[tid] = v;
    __syncthreads();
    for (int off = 1; off < SCAN_B; off <<= 1) {
        int t = (tid >= off) ? sm[tid - off] : 0;
        __syncthreads();
        sm[tid] += t;
        __syncthreads();
    }
    if (gid < n) rp[gid] = sm[tid] - v;           // exclusive
    if (tid == SCAN_B - 1) bsum[blockIdx.x] = sm[tid];
}

__global__ void k_scan2(int* __restrict__ bsum, int nb) {
    __shared__ int sm[SCAN_B];
    const int tid = threadIdx.x;
    int v = (tid < nb) ? bsum[tid] : 0;
    sm[tid] = v;
    __syncthreads();
    for (int off = 1; off < SCAN_B; off <<= 1) {
        int t = (tid >= off) ? sm[tid - off] : 0;
        __syncthreads();
        sm[tid] += t;
        __syncthreads();
    }
    if (tid < nb) bsum[tid] = sm[tid] - v;        // exclusive
}

__global__ void k_scan3(int* __restrict__ rp, const int* __restrict__ bsum, int n, int E) {
    const int gid = blockIdx.x * SCAN_B + threadIdx.x;
    if (gid < n) rp[gid] += bsum[gid / SCAN_B];
    if (gid == n) rp[n] = E;
}

// scatter (src, nrm) into CSR slots
__global__ void k_build(const int* __restrict__ src, const int* __restrict__ dst,
                        const float* __restrict__ dis, const int* __restrict__ rp,
                        int* __restrict__ fill, int2* __restrict__ edata, int E) {
    int e = blockIdx.x * blockDim.x + threadIdx.x;
    if (e >= E) return;
    int d = dst[e];
    int s = src[e];
    int pos = atomicAdd(&fill[d], 1);
    float nrm = dis[s] * dis[d];
    edata[rp[d] + pos] = make_int2(s, __float_as_int(nrm));
}

// GEMM, w3lsm-pattern: H[N,64] = X[N,K] @ W[K,64].
// Lane c holds W[:,c] in K VGPRs (loaded once per wave). Wave loops over its
// node chunk; X row address is wave-uniform (scalar/broadcast loads). One
// coalesced 256B store per node. No cross-lane ops, no address replication.
template<int K>
__global__ __launch_bounds__(256, K == 128 ? 2 : 4)
void k_wgemm(const float* __restrict__ X, const float* __restrict__ W,
             float* __restrict__ H, int N, int npw) {
    const int wid  = blockIdx.x * (blockDim.x >> 6) + (threadIdx.x >> 6);
    const int lane = threadIdx.x & 63;

    float w[K];
#pragma unroll
    for (int k = 0; k < K; ++k) w[k] = W[k * 64 + lane];

    const int n0 = wid * npw;
    const int n1 = min(n0 + npw, N);
    for (int node = n0; node < n1; ++node) {
        const int un = __builtin_amdgcn_readfirstlane(node);
        const float4* xr = (const float4*)(X + (size_t)un * K);
        float acc = 0.0f;
#pragma unroll
        for (int j = 0; j < K / 4; ++j) {
            float4 xv = xr[j];
            acc = fmaf(xv.x, w[4 * j + 0], acc);
            acc = fmaf(xv.y, w[4 * j + 1], acc);
            acc = fmaf(xv.z, w[4 * j + 2], acc);
            acc = fmaf(xv.w, w[4 * j + 3], acc);
        }
        H[(size_t)node * 64 + lane] = acc;
    }
}

// Wave-per-node aggregation, F=64, unroll-4 for memory-level parallelism.
template<bool BIAS_RELU>
__global__ void k_agg64(const float* __restrict__ H, const float* __restrict__ dis,
                        const int* __restrict__ rp, const int2* __restrict__ edata,
                        const float* __restrict__ bias, float* __restrict__ A, int N) {
    const int wave = threadIdx.x >> 6;
    const int lane = threadIdx.x & 63;
    const int node = blockIdx.x * (blockDim.x >> 6) + wave;
    if (node >= N) return;
    const float dd = dis[node];
    float a0 = H[(size_t)node * 64 + lane] * dd * dd;  // self-loop
    float a1 = 0.f, a2 = 0.f, a3 = 0.f;
    int e = rp[node];
    const int e1 = rp[node + 1];
    for (; e + 4 <= e1; e += 4) {
        int2 p0 = edata[e + 0];
        int2 p1 = edata[e + 1];
        int2 p2 = edata[e + 2];
        int2 p3 = edata[e + 3];
        float h0 = H[(size_t)p0.x * 64 + lane];
        float h1 = H[(size_t)p1.x * 64 + lane];
        float h2 = H[(size_t)p2.x * 64 + lane];
        float h3 = H[(size_t)p3.x * 64 + lane];
        a0 = fmaf(h0, __int_as_float(p0.y), a0);
        a1 = fmaf(h1, __int_as_float(p1.y), a1);
        a2 = fmaf(h2, __int_as_float(p2.y), a2);
        a3 = fmaf(h3, __int_as_float(p3.y), a3);
    }
    for (; e < e1; ++e) {
        int2 p = edata[e];
        a0 = fmaf(H[(size_t)p.x * 64 + lane], __int_as_float(p.y), a0);
    }
    float acc = (a0 + a1) + (a2 + a3);
    if (BIAS_RELU) acc = fmaxf(acc + bias[lane], 0.0f);
    A[(size_t)node * 64 + lane] = acc;
}

// Final layer: out[n,:40] = log_softmax(X[n,:64] @ W3 + b3).
// Same W-in-VGPR / X-uniform pattern.
__global__ __launch_bounds__(256, 4)
void k_w3lsm(const float* __restrict__ X, const float* __restrict__ W,
             const float* __restrict__ bias, float* __restrict__ out,
             int N, int npw) {
    const int wid  = blockIdx.x * (blockDim.x >> 6) + (threadIdx.x >> 6);
    const int lane = threadIdx.x & 63;
    const int cl   = (lane < 40) ? lane : 0;

    float w[64];
#pragma unroll
    for (int k = 0; k < 64; ++k) w[k] = W[k * 40 + cl];
    const float bv = bias[cl];

    const int n0 = wid * npw;
    const int n1 = min(n0 + npw, N);
    for (int node = n0; node < n1; ++node) {
        const int un = __builtin_amdgcn_readfirstlane(node);
        const float4* xr = (const float4*)(X + (size_t)un * 64);
        float acc = 0.0f;
#pragma unroll
        for (int j = 0; j < 16; ++j) {
            float4 xv = xr[j];
            acc = fmaf(xv.x, w[4 * j + 0], acc);
            acc = fmaf(xv.y, w[4 * j + 1], acc);
            acc = fmaf(xv.z, w[4 * j + 2], acc);
            acc = fmaf(xv.w, w[4 * j + 3], acc);
        }
        float v = (lane < 40) ? acc + bv : -INFINITY;
        float m = v;
#pragma unroll
        for (int o = 32; o > 0; o >>= 1) m = fmaxf(m, __shfl_xor(m, o, 64));
        float ex = (lane < 40) ? expf(v - m) : 0.0f;
        float s = ex;
#pragma unroll
        for (int o = 32; o > 0; o >>= 1) s += __shfl_xor(s, o, 64);
        if (lane < 40) out[(size_t)node * 40 + lane] = v - m - logf(s);
    }
}

extern "C" void kernel_launch(void* const* d_in, const int* in_sizes, int n_in,
                              void* d_out, int out_size, void* d_ws, size_t ws_size,
                              hipStream_t stream) {
    const float* x  = (const float*)d_in[0];
    const int*   ei = (const int*)d_in[1];
    const float* W1 = (const float*)d_in[2];
    const float* b1 = (const float*)d_in[3];
    const float* W2 = (const float*)d_in[4];
    const float* b2 = (const float*)d_in[5];
    const float* W3 = (const float*)d_in[6];
    const float* b3 = (const float*)d_in[7];
    float* out = (float*)d_out;

    const int N = in_sizes[0] / 128;
    const int E = in_sizes[1] / 2;
    const int* src = ei;
    const int* dst = ei + E;

    // ---- workspace layout (8B-aligned first) ----
    char* ws = (char*)d_ws;
    int2*  edata = (int2*)ws;                 ws += (size_t)E * sizeof(int2);       // 9.6 MB
    float* hbuf  = (float*)ws;                ws += (size_t)N * 64 * sizeof(float); // 25.6 MB
    float* abuf  = (float*)ws;                ws += (size_t)N * 64 * sizeof(float); // 25.6 MB
    int*   cnt   = (int*)ws;                  ws += (size_t)N * sizeof(int);
    int*   fill  = (int*)ws;                  ws += (size_t)N * sizeof(int);
    int*   rp    = (int*)ws;                  ws += (size_t)(N + 1) * sizeof(int);
    int*   bsum  = (int*)ws;                  ws += (size_t)SCAN_B * sizeof(int);
    float* dis   = (float*)ws;                ws += (size_t)N * sizeof(float);

    const int B = 256;
    const int nb = cdiv(N, SCAN_B);

    // ---- CSR build ----
    k_zero_i32<<<cdiv(2 * N, B), B, 0, stream>>>(cnt, 2 * N);  // cnt + fill adjacent
    k_hist<<<cdiv(E, B), B, 0, stream>>>(dst, cnt, E);
    k_dis<<<cdiv(N, B), B, 0, stream>>>(cnt, dis, N);
    k_scan1<<<nb, SCAN_B, 0, stream>>>(cnt, rp, bsum, N);
    k_scan2<<<1, SCAN_B, 0, stream>>>(bsum, nb);
    k_scan3<<<cdiv(N + 1, SCAN_B), SCAN_B, 0, stream>>>(rp, bsum, N, E);
    k_build<<<cdiv(E, B), B, 0, stream>>>(src, dst, dis, rp, fill, edata, E);

    // waves for the w-in-vgpr kernels: 4096 waves = 1024 blocks x 4
    const int NW = 4096;
    const int npw = cdiv(N, NW);

    // ---- layer 1: x[N,128] @ W1 -> hbuf; aggregate+bias+relu -> abuf ----
    k_wgemm<128><<<NW / 4, B, 0, stream>>>(x, W1, hbuf, N, npw);
    k_agg64<true><<<cdiv(N, 4), B, 0, stream>>>(hbuf, dis, rp, edata, b1, abuf, N);

    // ---- layer 2 ----
    k_wgemm<64><<<NW / 4, B, 0, stream>>>(abuf, W2, hbuf, N, npw);
    k_agg64<true><<<cdiv(N, 4), B, 0, stream>>>(hbuf, dis, rp, edata, b2, abuf, N);

    // ---- layer 3 reordered: (A h2) W3 + b3 -> log_softmax ----
    k_agg64<false><<<cdiv(N, 4), B, 0, stream>>>(abuf, dis, rp, edata, nullptr, hbuf, N);
    k_w3lsm<<<NW / 4, B, 0, stream>>>(hbuf, W3, b3, out, N, npw);
}

// Round 9
// 472.405 us; speedup vs baseline: 1.1824x; 1.1824x over previous
//
#include <hip/hip_runtime.h>
#include <math.h>

// ---------------------------------------------------------------------------
// 3-layer GCN, CSR-gather formulation.
// Round 9: LDS-tiled GEMM. R7's 4x4 reg tile fetched operands from L1 per
// k-group (latency-bound, 68us); R8's W-in-VGPR wave loop was worse (compiler
// re-loaded W in-loop, serial per-node chain, 119us). Now: stage X-tile
// (padded) + W in LDS once per block, one barrier, feed the 4x4 tile from
// LDS -> VALU-bound (~10us of FMA for K=128).
// N=100000, E=1200000, F: 128 -> 64 -> 64 -> 40
// ---------------------------------------------------------------------------

static inline int cdiv(long a, int b) { return (int)((a + b - 1) / b); }

__global__ void k_zero_i32(int* __restrict__ p, int n) {
    int i = blockIdx.x * blockDim.x + threadIdx.x;
    if (i < n) p[i] = 0;
}

__global__ void k_hist(const int* __restrict__ dst, int* __restrict__ cnt, int E) {
    int i = blockIdx.x * blockDim.x + threadIdx.x;
    if (i < E) atomicAdd(&cnt[dst[i]], 1);
}

__global__ void k_dis(const int* __restrict__ cnt, float* __restrict__ dis, int n) {
    int i = blockIdx.x * blockDim.x + threadIdx.x;
    if (i < n) dis[i] = rsqrtf(1.0f + (float)cnt[i]);  // +1 self-loop
}

// ---- 3-step exclusive scan of cnt[0..n) into rp[0..n], rp[n]=E ----
#define SCAN_B 1024
__global__ void k_scan1(const int* __restrict__ cnt, int* __restrict__ rp,
                        int* __restrict__ bsum, int n) {
    __shared__ int sm[SCAN_B];
    const int tid = threadIdx.x;
    const int gid = blockIdx.x * SCAN_B + tid;
    int v = (gid < n) ? cnt[gid] : 0;
    sm[tid] = v;
    __syncthreads();
    for (int off = 1; off < SCAN_B; off <<= 1) {
        int t = (tid >= off) ? sm[tid - off] : 0;
        __syncthreads();
        sm[tid] += t;
        __syncthreads();
    }
    if (gid < n) rp[gid] = sm[tid] - v;           // exclusive
    if (tid == SCAN_B - 1) bsum[blockIdx.x] = sm[tid];
}

__global__ void k_scan2(int* __restrict__ bsum, int nb) {
    __shared__ int sm[SCAN_B];
    const int tid = threadIdx.x;
    int v = (tid < nb) ? bsum[tid] : 0;
    sm[tid] = v;
    __syncthreads();
    for (int off = 1; off < SCAN_B; off <<= 1) {
        int t = (tid >= off) ? sm[tid - off] : 0;
        __syncthreads();
        sm[tid] += t;
        __syncthreads();
    }
    if (tid < nb) bsum[tid] = sm[tid] - v;        // exclusive
}

__global__ void k_scan3(int* __restrict__ rp, const int* __restrict__ bsum, int n, int E) {
    const int gid = blockIdx.x * SCAN_B + threadIdx.x;
    if (gid < n) rp[gid] += bsum[gid / SCAN_B];
    if (gid == n) rp[n] = E;
}

// scatter (src, nrm) into CSR slots
__global__ void k_build(const int* __restrict__ src, const int* __restrict__ dst,
                        const float* __restrict__ dis, const int* __restrict__ rp,
                        int* __restrict__ fill, int2* __restrict__ edata, int E) {
    int e = blockIdx.x * blockDim.x + threadIdx.x;
    if (e >= E) return;
    int d = dst[e];
    int s = src[e];
    int pos = atomicAdd(&fill[d], 1);
    float nrm = dis[s] * dis[d];
    edata[rp[d] + pos] = make_int2(s, __float_as_int(nrm));
}

__device__ __forceinline__ void fma4(float a, const float4& w, float4& acc) {
    acc.x = fmaf(a, w.x, acc.x);
    acc.y = fmaf(a, w.y, acc.y);
    acc.z = fmaf(a, w.z, acc.z);
    acc.w = fmaf(a, w.w, acc.w);
}

// LDS-tiled GEMM: H[N,64] = X[N,K] @ W[K,64].
// Block = 256 threads -> 64-row x 64-col tile, 4x4 per thread.
// X tile staged in LDS with +4-float row pad (de-conflicts the ty quad);
// W staged in LDS [k][col] (2-way access = free). One barrier per block.
template<int K>
__global__ __launch_bounds__(256, 2)
void k_gemm_lds(const float* __restrict__ X, const float* __restrict__ W,
                float* __restrict__ H, int N) {
    constexpr int KP = K + 4;                 // padded X row stride (floats)
    __shared__ float xs[64 * KP];
    __shared__ float wsh[K * 64];
    const int tid = threadIdx.x;
    const int tx = tid & 15;                  // col group (4 cols)
    const int ty = tid >> 4;                  // row group (4 rows)
    const int row0 = blockIdx.x * 64;

    // stage W: K*16 float4, fully coalesced
    {
        const float4* Wg = (const float4*)W;
        float4* Wl = (float4*)wsh;
#pragma unroll
        for (int i = 0; i < K * 16 / 256; ++i)
            Wl[i * 256 + tid] = Wg[i * 256 + tid];
    }
    // stage X tile: 64 rows x K floats (row-clamped), padded LDS rows
    {
        constexpr int F4 = K / 4;             // float4 per row
        for (int i = tid; i < 64 * F4; i += 256) {
            int r = i / F4, c = i - r * F4;
            int gr = min(row0 + r, N - 1);
            float4 v = *(const float4*)(X + (size_t)gr * K + c * 4);
            *(float4*)(xs + r * KP + c * 4) = v;
        }
    }
    __syncthreads();

    float4 acc0 = {0.f, 0.f, 0.f, 0.f};
    float4 acc1 = {0.f, 0.f, 0.f, 0.f};
    float4 acc2 = {0.f, 0.f, 0.f, 0.f};
    float4 acc3 = {0.f, 0.f, 0.f, 0.f};

    const float* xr0 = xs + (ty * 4 + 0) * KP;
    const float* xr1 = xs + (ty * 4 + 1) * KP;
    const float* xr2 = xs + (ty * 4 + 2) * KP;
    const float* xr3 = xs + (ty * 4 + 3) * KP;

#pragma unroll 2
    for (int k = 0; k < K; k += 4) {
        float4 w0 = *(const float4*)(wsh + (k + 0) * 64 + tx * 4);
        float4 w1 = *(const float4*)(wsh + (k + 1) * 64 + tx * 4);
        float4 w2 = *(const float4*)(wsh + (k + 2) * 64 + tx * 4);
        float4 w3 = *(const float4*)(wsh + (k + 3) * 64 + tx * 4);
        float4 xa = *(const float4*)(xr0 + k);
        float4 xb = *(const float4*)(xr1 + k);
        float4 xc = *(const float4*)(xr2 + k);
        float4 xd = *(const float4*)(xr3 + k);

        fma4(xa.x, w0, acc0); fma4(xa.y, w1, acc0); fma4(xa.z, w2, acc0); fma4(xa.w, w3, acc0);
        fma4(xb.x, w0, acc1); fma4(xb.y, w1, acc1); fma4(xb.z, w2, acc1); fma4(xb.w, w3, acc1);
        fma4(xc.x, w0, acc2); fma4(xc.y, w1, acc2); fma4(xc.z, w2, acc2); fma4(xc.w, w3, acc2);
        fma4(xd.x, w0, acc3); fma4(xd.y, w1, acc3); fma4(xd.z, w2, acc3); fma4(xd.w, w3, acc3);
    }

    const int r = row0 + ty * 4;
    float* hp = H + (size_t)r * 64 + tx * 4;
    if (r + 0 < N) *(float4*)(hp + 0 * 64) = acc0;
    if (r + 1 < N) *(float4*)(hp + 1 * 64) = acc1;
    if (r + 2 < N) *(float4*)(hp + 2 * 64) = acc2;
    if (r + 3 < N) *(float4*)(hp + 3 * 64) = acc3;
}

// Wave-per-node aggregation, F=64, unroll-4 for memory-level parallelism.
template<bool BIAS_RELU>
__global__ void k_agg64(const float* __restrict__ H, const float* __restrict__ dis,
                        const int* __restrict__ rp, const int2* __restrict__ edata,
                        const float* __restrict__ bias, float* __restrict__ A, int N) {
    const int wave = threadIdx.x >> 6;
    const int lane = threadIdx.x & 63;
    const int node = blockIdx.x * (blockDim.x >> 6) + wave;
    if (node >= N) return;
    const float dd = dis[node];
    float a0 = H[(size_t)node * 64 + lane] * dd * dd;  // self-loop
    float a1 = 0.f, a2 = 0.f, a3 = 0.f;
    int e = rp[node];
    const int e1 = rp[node + 1];
    for (; e + 4 <= e1; e += 4) {
        int2 p0 = edata[e + 0];
        int2 p1 = edata[e + 1];
        int2 p2 = edata[e + 2];
        int2 p3 = edata[e + 3];
        float h0 = H[(size_t)p0.x * 64 + lane];
        float h1 = H[(size_t)p1.x * 64 + lane];
        float h2 = H[(size_t)p2.x * 64 + lane];
        float h3 = H[(size_t)p3.x * 64 + lane];
        a0 = fmaf(h0, __int_as_float(p0.y), a0);
        a1 = fmaf(h1, __int_as_float(p1.y), a1);
        a2 = fmaf(h2, __int_as_float(p2.y), a2);
        a3 = fmaf(h3, __int_as_float(p3.y), a3);
    }
    for (; e < e1; ++e) {
        int2 p = edata[e];
        a0 = fmaf(H[(size_t)p.x * 64 + lane], __int_as_float(p.y), a0);
    }
    float acc = (a0 + a1) + (a2 + a3);
    if (BIAS_RELU) acc = fmaxf(acc + bias[lane], 0.0f);
    A[(size_t)node * 64 + lane] = acc;
}

// Final layer: out[n,:40] = log_softmax(X[n,:64] @ W3 + b3).
// Lane c holds W3[:,c] in 64 VGPRs; X row via wave-uniform loads.
__global__ __launch_bounds__(256, 4)
void k_w3lsm(const float* __restrict__ X, const float* __restrict__ W,
             const float* __restrict__ bias, float* __restrict__ out,
             int N, int npw) {
    const int wid  = blockIdx.x * (blockDim.x >> 6) + (threadIdx.x >> 6);
    const int lane = threadIdx.x & 63;
    const int cl   = (lane < 40) ? lane : 0;

    float w[64];
#pragma unroll
    for (int k = 0; k < 64; ++k) w[k] = W[k * 40 + cl];
    const float bv = bias[cl];

    const int n0 = wid * npw;
    const int n1 = min(n0 + npw, N);
    for (int node = n0; node < n1; ++node) {
        const int un = __builtin_amdgcn_readfirstlane(node);
        const float4* xr = (const float4*)(X + (size_t)un * 64);
        float acc = 0.0f;
#pragma unroll
        for (int j = 0; j < 16; ++j) {
            float4 xv = xr[j];
            acc = fmaf(xv.x, w[4 * j + 0], acc);
            acc = fmaf(xv.y, w[4 * j + 1], acc);
            acc = fmaf(xv.z, w[4 * j + 2], acc);
            acc = fmaf(xv.w, w[4 * j + 3], acc);
        }
        float v = (lane < 40) ? acc + bv : -INFINITY;
        float m = v;
#pragma unroll
        for (int o = 32; o > 0; o >>= 1) m = fmaxf(m, __shfl_xor(m, o, 64));
        float ex = (lane < 40) ? expf(v - m) : 0.0f;
        float s = ex;
#pragma unroll
        for (int o = 32; o > 0; o >>= 1) s += __shfl_xor(s, o, 64);
        if (lane < 40) out[(size_t)node * 40 + lane] = v - m - logf(s);
    }
}

extern "C" void kernel_launch(void* const* d_in, const int* in_sizes, int n_in,
                              void* d_out, int out_size, void* d_ws, size_t ws_size,
                              hipStream_t stream) {
    const float* x  = (const float*)d_in[0];
    const int*   ei = (const int*)d_in[1];
    const float* W1 = (const float*)d_in[2];
    const float* b1 = (const float*)d_in[3];
    const float* W2 = (const float*)d_in[4];
    const float* b2 = (const float*)d_in[5];
    const float* W3 = (const float*)d_in[6];
    const float* b3 = (const float*)d_in[7];
    float* out = (float*)d_out;

    const int N = in_sizes[0] / 128;
    const int E = in_sizes[1] / 2;
    const int* src = ei;
    const int* dst = ei + E;

    // ---- workspace layout (8B-aligned first) ----
    char* ws = (char*)d_ws;
    int2*  edata = (int2*)ws;                 ws += (size_t)E * sizeof(int2);       // 9.6 MB
    float* hbuf  = (float*)ws;                ws += (size_t)N * 64 * sizeof(float); // 25.6 MB
    float* abuf  = (float*)ws;                ws += (size_t)N * 64 * sizeof(float); // 25.6 MB
    int*   cnt   = (int*)ws;                  ws += (size_t)N * sizeof(int);
    int*   fill  = (int*)ws;                  ws += (size_t)N * sizeof(int);
    int*   rp    = (int*)ws;                  ws += (size_t)(N + 1) * sizeof(int);
    int*   bsum  = (int*)ws;                  ws += (size_t)SCAN_B * sizeof(int);
    float* dis   = (float*)ws;                ws += (size_t)N * sizeof(float);

    const int B = 256;
    const int nb = cdiv(N, SCAN_B);

    // ---- CSR build ----
    k_zero_i32<<<cdiv(2 * N, B), B, 0, stream>>>(cnt, 2 * N);  // cnt + fill adjacent
    k_hist<<<cdiv(E, B), B, 0, stream>>>(dst, cnt, E);
    k_dis<<<cdiv(N, B), B, 0, stream>>>(cnt, dis, N);
    k_scan1<<<nb, SCAN_B, 0, stream>>>(cnt, rp, bsum, N);
    k_scan2<<<1, SCAN_B, 0, stream>>>(bsum, nb);
    k_scan3<<<cdiv(N + 1, SCAN_B), SCAN_B, 0, stream>>>(rp, bsum, N, E);
    k_build<<<cdiv(E, B), B, 0, stream>>>(src, dst, dis, rp, fill, edata, E);

    // ---- layer 1: x[N,128] @ W1 -> hbuf; aggregate+bias+relu -> abuf ----
    k_gemm_lds<128><<<cdiv(N, 64), B, 0, stream>>>(x, W1, hbuf, N);
    k_agg64<true><<<cdiv(N, 4), B, 0, stream>>>(hbuf, dis, rp, edata, b1, abuf, N);

    // ---- layer 2 ----
    k_gemm_lds<64><<<cdiv(N, 64), B, 0, stream>>>(abuf, W2, hbuf, N);
    k_agg64<true><<<cdiv(N, 4), B, 0, stream>>>(hbuf, dis, rp, edata, b2, abuf, N);

    // ---- layer 3 reordered: (A h2) W3 + b3 -> log_softmax ----
    k_agg64<false><<<cdiv(N, 4), B, 0, stream>>>(abuf, dis, rp, edata, nullptr, hbuf, N);
    const int NW = 4096;                       // 1024 blocks x 4 waves
    const int npw = cdiv(N, NW);
    k_w3lsm<<<NW / 4, B, 0, stream>>>(hbuf, W3, b3, out, N, npw);
}

// Round 10
// 455.310 us; speedup vs baseline: 1.2268x; 1.0375x over previous
//
#include <hip/hip_runtime.h>
#include <math.h>

// ---------------------------------------------------------------------------
// 3-layer GCN, CSR-gather formulation.
// Round 10: (a) symmetric norm factorized: A[d] = dis[d]*(Hs[d]+sum Hs[s])
// with Hs = h*dis applied in the GEMM epilogue -> CSR stores src only (4B),
// aggregation is a pure segmented row-sum. (b) agg restructured quad-per-edge:
// 16 lanes x float4 per 256B row, 4 quads walk interleaved edges, unroll 2
// -> 8 rows in flight per wave (was 4) for the latency-bound gather.
// N=100000, E=1200000, F: 128 -> 64 -> 64 -> 40
// ---------------------------------------------------------------------------

static inline int cdiv(long a, int b) { return (int)((a + b - 1) / b); }

__global__ void k_zero_i32(int* __restrict__ p, int n) {
    int i = blockIdx.x * blockDim.x + threadIdx.x;
    if (i < n) p[i] = 0;
}

__global__ void k_hist(const int* __restrict__ dst, int* __restrict__ cnt, int E) {
    int i = blockIdx.x * blockDim.x + threadIdx.x;
    if (i < E) atomicAdd(&cnt[dst[i]], 1);
}

__global__ void k_dis(const int* __restrict__ cnt, float* __restrict__ dis, int n) {
    int i = blockIdx.x * blockDim.x + threadIdx.x;
    if (i < n) dis[i] = rsqrtf(1.0f + (float)cnt[i]);  // +1 self-loop
}

// ---- 3-step exclusive scan of cnt[0..n) into rp[0..n], rp[n]=E ----
#define SCAN_B 1024
__global__ void k_scan1(const int* __restrict__ cnt, int* __restrict__ rp,
                        int* __restrict__ bsum, int n) {
    __shared__ int sm[SCAN_B];
    const int tid = threadIdx.x;
    const int gid = blockIdx.x * SCAN_B + tid;
    int v = (gid < n) ? cnt[gid] : 0;
    sm[tid] = v;
    __syncthreads();
    for (int off = 1; off < SCAN_B; off <<= 1) {
        int t = (tid >= off) ? sm[tid - off] : 0;
        __syncthreads();
        sm[tid] += t;
        __syncthreads();
    }
    if (gid < n) rp[gid] = sm[tid] - v;           // exclusive
    if (tid == SCAN_B - 1) bsum[blockIdx.x] = sm[tid];
}

__global__ void k_scan2(int* __restrict__ bsum, int nb) {
    __shared__ int sm[SCAN_B];
    const int tid = threadIdx.x;
    int v = (tid < nb) ? bsum[tid] : 0;
    sm[tid] = v;
    __syncthreads();
    for (int off = 1; off < SCAN_B; off <<= 1) {
        int t = (tid >= off) ? sm[tid - off] : 0;
        __syncthreads();
        sm[tid] += t;
        __syncthreads();
    }
    if (tid < nb) bsum[tid] = sm[tid] - v;        // exclusive
}

__global__ void k_scan3(int* __restrict__ rp, const int* __restrict__ bsum, int n, int E) {
    const int gid = blockIdx.x * SCAN_B + threadIdx.x;
    if (gid < n) rp[gid] += bsum[gid / SCAN_B];
    if (gid == n) rp[n] = E;
}

// scatter src index into CSR slots (norm factored out -> 4 B/edge)
__global__ void k_build(const int* __restrict__ src, const int* __restrict__ dst,
                        const int* __restrict__ rp, int* __restrict__ fill,
                        int* __restrict__ esrc, int E) {
    int e = blockIdx.x * blockDim.x + threadIdx.x;
    if (e >= E) return;
    int d = dst[e];
    int pos = atomicAdd(&fill[d], 1);
    esrc[rp[d] + pos] = src[e];
}

__device__ __forceinline__ void fma4(float a, const float4& w, float4& acc) {
    acc.x = fmaf(a, w.x, acc.x);
    acc.y = fmaf(a, w.y, acc.y);
    acc.z = fmaf(a, w.z, acc.z);
    acc.w = fmaf(a, w.w, acc.w);
}

// LDS-tiled GEMM with fused dis-scale: Hs[N,64] = (X[N,K] @ W[K,64]) * dis[row].
template<int K>
__global__ __launch_bounds__(256, 2)
void k_gemm_lds(const float* __restrict__ X, const float* __restrict__ W,
                const float* __restrict__ dis, float* __restrict__ H, int N) {
    constexpr int KP = K + 4;                 // padded X row stride (floats)
    __shared__ float xs[64 * KP];
    __shared__ float wsh[K * 64];
    const int tid = threadIdx.x;
    const int tx = tid & 15;                  // col group (4 cols)
    const int ty = tid >> 4;                  // row group (4 rows)
    const int row0 = blockIdx.x * 64;

    // stage W: K*16 float4, fully coalesced
    {
        const float4* Wg = (const float4*)W;
        float4* Wl = (float4*)wsh;
#pragma unroll
        for (int i = 0; i < K * 16 / 256; ++i)
            Wl[i * 256 + tid] = Wg[i * 256 + tid];
    }
    // stage X tile: 64 rows x K floats (row-clamped), padded LDS rows
    {
        constexpr int F4 = K / 4;             // float4 per row
        for (int i = tid; i < 64 * F4; i += 256) {
            int r = i / F4, c = i - r * F4;
            int gr = min(row0 + r, N - 1);
            float4 v = *(const float4*)(X + (size_t)gr * K + c * 4);
            *(float4*)(xs + r * KP + c * 4) = v;
        }
    }
    __syncthreads();

    float4 acc0 = {0.f, 0.f, 0.f, 0.f};
    float4 acc1 = {0.f, 0.f, 0.f, 0.f};
    float4 acc2 = {0.f, 0.f, 0.f, 0.f};
    float4 acc3 = {0.f, 0.f, 0.f, 0.f};

    const float* xr0 = xs + (ty * 4 + 0) * KP;
    const float* xr1 = xs + (ty * 4 + 1) * KP;
    const float* xr2 = xs + (ty * 4 + 2) * KP;
    const float* xr3 = xs + (ty * 4 + 3) * KP;

#pragma unroll 2
    for (int k = 0; k < K; k += 4) {
        float4 w0 = *(const float4*)(wsh + (k + 0) * 64 + tx * 4);
        float4 w1 = *(const float4*)(wsh + (k + 1) * 64 + tx * 4);
        float4 w2 = *(const float4*)(wsh + (k + 2) * 64 + tx * 4);
        float4 w3 = *(const float4*)(wsh + (k + 3) * 64 + tx * 4);
        float4 xa = *(const float4*)(xr0 + k);
        float4 xb = *(const float4*)(xr1 + k);
        float4 xc = *(const float4*)(xr2 + k);
        float4 xd = *(const float4*)(xr3 + k);

        fma4(xa.x, w0, acc0); fma4(xa.y, w1, acc0); fma4(xa.z, w2, acc0); fma4(xa.w, w3, acc0);
        fma4(xb.x, w0, acc1); fma4(xb.y, w1, acc1); fma4(xb.z, w2, acc1); fma4(xb.w, w3, acc1);
        fma4(xc.x, w0, acc2); fma4(xc.y, w1, acc2); fma4(xc.z, w2, acc2); fma4(xc.w, w3, acc2);
        fma4(xd.x, w0, acc3); fma4(xd.y, w1, acc3); fma4(xd.z, w2, acc3); fma4(xd.w, w3, acc3);
    }

    const int r = row0 + ty * 4;
    float* hp = H + (size_t)r * 64 + tx * 4;
    if (r + 0 < N) { float d0 = dis[r + 0];
        acc0.x *= d0; acc0.y *= d0; acc0.z *= d0; acc0.w *= d0;
        *(float4*)(hp + 0 * 64) = acc0; }
    if (r + 1 < N) { float d1 = dis[r + 1];
        acc1.x *= d1; acc1.y *= d1; acc1.z *= d1; acc1.w *= d1;
        *(float4*)(hp + 1 * 64) = acc1; }
    if (r + 2 < N) { float d2 = dis[r + 2];
        acc2.x *= d2; acc2.y *= d2; acc2.z *= d2; acc2.w *= d2;
        *(float4*)(hp + 2 * 64) = acc2; }
    if (r + 3 < N) { float d3 = dis[r + 3];
        acc3.x *= d3; acc3.y *= d3; acc3.z *= d3; acc3.w *= d3;
        *(float4*)(hp + 3 * 64) = acc3; }
}

// Wave-per-node segmented row-sum, quad-per-edge.
// Input Hs = h*dis.  t = dis[d] * (Hs[d] + sum_{in-edges} Hs[s]).
// MODE 0: A = relu(t + bias)              (layer 1)
// MODE 1: A = relu(t + bias) * dis[d]     (layer 2 -> pre-scaled for layer-3 agg)
// MODE 2: A = t                           (layer 3 pre-GEMM aggregate)
template<int MODE>
__global__ __launch_bounds__(256, 8)
void k_agg(const float* __restrict__ Hs, const float* __restrict__ dis,
           const int* __restrict__ rp, const int* __restrict__ esrc,
           const float* __restrict__ bias, float* __restrict__ A, int N) {
    const int wave = threadIdx.x >> 6;
    const int lane = threadIdx.x & 63;
    const int node = blockIdx.x * (blockDim.x >> 6) + wave;
    if (node >= N) return;
    const int q  = lane >> 4;          // quad 0..3 -> interleaved edges
    const int f4 = lane & 15;          // float4 index within the 64-f row

    const int e0 = rp[node];
    const int e1 = rp[node + 1];
    float4 acc = {0.f, 0.f, 0.f, 0.f};
    int e = e0 + q;
    for (; e + 4 < e1; e += 8) {       // 2 edges per quad per round: 8 rows in flight
        int s0 = esrc[e];
        int s1 = esrc[e + 4];
        float4 h0 = *(const float4*)(Hs + (size_t)s0 * 64 + f4 * 4);
        float4 h1 = *(const float4*)(Hs + (size_t)s1 * 64 + f4 * 4);
        acc.x += h0.x + h1.x;
        acc.y += h0.y + h1.y;
        acc.z += h0.z + h1.z;
        acc.w += h0.w + h1.w;
    }
    for (; e < e1; e += 4) {
        int s = esrc[e];
        float4 h = *(const float4*)(Hs + (size_t)s * 64 + f4 * 4);
        acc.x += h.x; acc.y += h.y; acc.z += h.z; acc.w += h.w;
    }
    // cross-quad reduce (after: all lanes hold the full row sum)
    acc.x += __shfl_xor(acc.x, 16, 64);
    acc.y += __shfl_xor(acc.y, 16, 64);
    acc.z += __shfl_xor(acc.z, 16, 64);
    acc.w += __shfl_xor(acc.w, 16, 64);
    acc.x += __shfl_xor(acc.x, 32, 64);
    acc.y += __shfl_xor(acc.y, 32, 64);
    acc.z += __shfl_xor(acc.z, 32, 64);
    acc.w += __shfl_xor(acc.w, 32, 64);

    if (lane < 16) {
        const float dd = dis[node];
        float4 self = *(const float4*)(Hs + (size_t)node * 64 + lane * 4);
        float4 v;
        v.x = (acc.x + self.x) * dd;
        v.y = (acc.y + self.y) * dd;
        v.z = (acc.z + self.z) * dd;
        v.w = (acc.w + self.w) * dd;
        if (MODE == 0 || MODE == 1) {
            float4 bv = ((const float4*)bias)[lane];
            v.x = fmaxf(v.x + bv.x, 0.f);
            v.y = fmaxf(v.y + bv.y, 0.f);
            v.z = fmaxf(v.z + bv.z, 0.f);
            v.w = fmaxf(v.w + bv.w, 0.f);
        }
        if (MODE == 1) { v.x *= dd; v.y *= dd; v.z *= dd; v.w *= dd; }
        *(float4*)(A + (size_t)node * 64 + lane * 4) = v;
    }
}

// Final layer: out[n,:40] = log_softmax(X[n,:64] @ W3 + b3).
// Lane c holds W3[:,c] in 64 VGPRs; X row via wave-uniform loads.
__global__ __launch_bounds__(256, 4)
void k_w3lsm(const float* __restrict__ X, const float* __restrict__ W,
             const float* __restrict__ bias, float* __restrict__ out,
             int N, int npw) {
    const int wid  = blockIdx.x * (blockDim.x >> 6) + (threadIdx.x >> 6);
    const int lane = threadIdx.x & 63;
    const int cl   = (lane < 40) ? lane : 0;

    float w[64];
#pragma unroll
    for (int k = 0; k < 64; ++k) w[k] = W[k * 40 + cl];
    const float bv = bias[cl];

    const int n0 = wid * npw;
    const int n1 = min(n0 + npw, N);
    for (int node = n0; node < n1; ++node) {
        const int un = __builtin_amdgcn_readfirstlane(node);
        const float4* xr = (const float4*)(X + (size_t)un * 64);
        float acc = 0.0f;
#pragma unroll
        for (int j = 0; j < 16; ++j) {
            float4 xv = xr[j];
            acc = fmaf(xv.x, w[4 * j + 0], acc);
            acc = fmaf(xv.y, w[4 * j + 1], acc);
            acc = fmaf(xv.z, w[4 * j + 2], acc);
            acc = fmaf(xv.w, w[4 * j + 3], acc);
        }
        float v = (lane < 40) ? acc + bv : -INFINITY;
        float m = v;
#pragma unroll
        for (int o = 32; o > 0; o >>= 1) m = fmaxf(m, __shfl_xor(m, o, 64));
        float ex = (lane < 40) ? expf(v - m) : 0.0f;
        float s = ex;
#pragma unroll
        for (int o = 32; o > 0; o >>= 1) s += __shfl_xor(s, o, 64);
        if (lane < 40) out[(size_t)node * 40 + lane] = v - m - logf(s);
    }
}

extern "C" void kernel_launch(void* const* d_in, const int* in_sizes, int n_in,
                              void* d_out, int out_size, void* d_ws, size_t ws_size,
                              hipStream_t stream) {
    const float* x  = (const float*)d_in[0];
    const int*   ei = (const int*)d_in[1];
    const float* W1 = (const float*)d_in[2];
    const float* b1 = (const float*)d_in[3];
    const float* W2 = (const float*)d_in[4];
    const float* b2 = (const float*)d_in[5];
    const float* W3 = (const float*)d_in[6];
    const float* b3 = (const float*)d_in[7];
    float* out = (float*)d_out;

    const int N = in_sizes[0] / 128;
    const int E = in_sizes[1] / 2;
    const int* src = ei;
    const int* dst = ei + E;

    // ---- workspace layout ----
    char* ws = (char*)d_ws;
    float* hbuf  = (float*)ws;                ws += (size_t)N * 64 * sizeof(float); // 25.6 MB
    float* abuf  = (float*)ws;                ws += (size_t)N * 64 * sizeof(float); // 25.6 MB
    int*   esrc  = (int*)ws;                  ws += (size_t)E * sizeof(int);        // 4.8 MB
    int*   cnt   = (int*)ws;                  ws += (size_t)N * sizeof(int);
    int*   fill  = (int*)ws;                  ws += (size_t)N * sizeof(int);
    int*   rp    = (int*)ws;                  ws += (size_t)(N + 1) * sizeof(int);
    int*   bsum  = (int*)ws;                  ws += (size_t)SCAN_B * sizeof(int);
    float* dis   = (float*)ws;                ws += (size_t)N * sizeof(float);

    const int B = 256;
    const int nb = cdiv(N, SCAN_B);

    // ---- CSR build ----
    k_zero_i32<<<cdiv(2 * N, B), B, 0, stream>>>(cnt, 2 * N);  // cnt + fill adjacent
    k_hist<<<cdiv(E, B), B, 0, stream>>>(dst, cnt, E);
    k_dis<<<cdiv(N, B), B, 0, stream>>>(cnt, dis, N);
    k_scan1<<<nb, SCAN_B, 0, stream>>>(cnt, rp, bsum, N);
    k_scan2<<<1, SCAN_B, 0, stream>>>(bsum, nb);
    k_scan3<<<cdiv(N + 1, SCAN_B), SCAN_B, 0, stream>>>(rp, bsum, N, E);
    k_build<<<cdiv(E, B), B, 0, stream>>>(src, dst, rp, fill, esrc, E);

    // ---- layer 1: Hs1 = (x@W1)*dis; a1 = relu(dis*(sum)+b1) ----
    k_gemm_lds<128><<<cdiv(N, 64), B, 0, stream>>>(x, W1, dis, hbuf, N);
    k_agg<0><<<cdiv(N, 4), B, 0, stream>>>(hbuf, dis, rp, esrc, b1, abuf, N);

    // ---- layer 2: Hs2 = (a1@W2)*dis; a2s = relu(dis*(sum)+b2)*dis ----
    k_gemm_lds<64><<<cdiv(N, 64), B, 0, stream>>>(abuf, W2, dis, hbuf, N);
    k_agg<1><<<cdiv(N, 4), B, 0, stream>>>(hbuf, dis, rp, esrc, b2, abuf, N);

    // ---- layer 3: g = dis*(sum of a2s); out = log_softmax(g@W3 + b3) ----
    k_agg<2><<<cdiv(N, 4), B, 0, stream>>>(abuf, dis, rp, esrc, nullptr, hbuf, N);
    const int NW = 4096;                       // 1024 blocks x 4 waves
    const int npw = cdiv(N, NW);
    k_w3lsm<<<NW / 4, B, 0, stream>>>(hbuf, W3, b3, out, N, npw);
}